// Round 13
// baseline (549.479 us; speedup 1.0000x reference)
//
#include <hip/hip_runtime.h>
#include <hip/hip_bf16.h>
#include <math.h>

#define NB 16384      // tokens
#define DD 2048       // hidden dim
#define NE 8          // experts
#define TM 128
#define TN 128
#define BK 64
#define NKT (DD / BK)                      // 32 K-tiles
#define MT_PER_PASS (NB / TM + NE)         // 136 = 8 XCDs x 17 M-tile band
#define NT_TILES (DD / TN)                 // 16
#define GEMM_GRID (MT_PER_PASS * NT_TILES) // 2176

typedef float f32x4 __attribute__((ext_vector_type(4)));
typedef short bf16x8 __attribute__((ext_vector_type(8)));

__device__ __forceinline__ short f2bf(float f) {
  union { float f; unsigned u; } v; v.f = f;
  unsigned r = (v.u + 0x7FFFu + ((v.u >> 16) & 1u)) >> 16;  // RNE
  return (short)r;
}

__device__ __forceinline__ void gload16(const void* g, void* l) {
  __builtin_amdgcn_global_load_lds((const __attribute__((address_space(1))) void*)g,
                                   (__attribute__((address_space(3))) void*)l,
                                   16, 0, 0);
}

// ---- expert_w (E,D,D fp32, [d][f]) -> bf16 transposed Wt[e][f][d] ----
__global__ void conv_wT(const float* __restrict__ w, short* __restrict__ wt) {
  __shared__ float tile[64][68];
  int bid = blockIdx.x;
  int e = bid >> 10;
  int tt = bid & 1023;
  int d0 = (tt >> 5) << 6;
  int f0 = (tt & 31) << 6;
  const float* we = w + (size_t)e * DD * DD;
  int t = threadIdx.x;
  int col = (t & 15) << 2;
#pragma unroll
  for (int p = 0; p < 4; ++p) {
    int dl = (t >> 4) + p * 16;
    f32x4 v = *(const f32x4*)(we + (size_t)(d0 + dl) * DD + f0 + col);
    *(f32x4*)&tile[dl][col] = v;
  }
  __syncthreads();
  int fl = t >> 2;
  int ds = (t & 3) << 4;
  short tmp[16];
#pragma unroll
  for (int j = 0; j < 16; ++j) tmp[j] = f2bf(tile[ds + j][fl]);
  short* dst = wt + (size_t)e * DD * DD + (size_t)(f0 + fl) * DD + d0 + ds;
  *(bf16x8*)dst = *(const bf16x8*)tmp;
  *(bf16x8*)(dst + 8) = *(const bf16x8*)(tmp + 8);
}

// ---- fused: x -> bf16 conversion + gate logits (fp64) + top-2 softmax ----
__global__ void gate_conv(const float* __restrict__ x, const float* __restrict__ gw,
                          const float* __restrict__ gb, short* __restrict__ xb,
                          int* __restrict__ ridx, float* __restrict__ rw) {
  int wid = threadIdx.x >> 6;
  int lane = threadIdx.x & 63;
  int b = blockIdx.x * 4 + wid;
  const float* xr = x + (size_t)b * DD;
  short* xbr = xb + (size_t)b * DD;
  double acc[8];
#pragma unroll
  for (int e = 0; e < 8; ++e) acc[e] = 0.0;
#pragma unroll
  for (int it = 0; it < 4; ++it) {
    int d8 = (it * 64 + lane) * 8;
    f32x4 a = *(const f32x4*)(xr + d8);
    f32x4 c = *(const f32x4*)(xr + d8 + 4);
    bf16x8 o;
    o[0] = f2bf(a[0]); o[1] = f2bf(a[1]); o[2] = f2bf(a[2]); o[3] = f2bf(a[3]);
    o[4] = f2bf(c[0]); o[5] = f2bf(c[1]); o[6] = f2bf(c[2]); o[7] = f2bf(c[3]);
    *(bf16x8*)(xbr + d8) = o;
#pragma unroll
    for (int j = 0; j < 8; ++j) {
      float xv = (j < 4) ? a[j] : c[j - 4];
      double xd = (double)xv;
      f32x4 g0 = *(const f32x4*)(gw + (size_t)(d8 + j) * 8);
      f32x4 g1 = *(const f32x4*)(gw + (size_t)(d8 + j) * 8 + 4);
      acc[0] += xd * g0[0]; acc[1] += xd * g0[1];
      acc[2] += xd * g0[2]; acc[3] += xd * g0[3];
      acc[4] += xd * g1[0]; acc[5] += xd * g1[1];
      acc[6] += xd * g1[2]; acc[7] += xd * g1[3];
    }
  }
#pragma unroll
  for (int off = 32; off > 0; off >>= 1) {
#pragma unroll
    for (int e = 0; e < 8; ++e) acc[e] += __shfl_down(acc[e], off);
  }
  if (lane == 0) {
    double l[8];
#pragma unroll
    for (int e = 0; e < 8; ++e) l[e] = acc[e] + (double)gb[e];
    int i0 = 0;
#pragma unroll
    for (int e = 1; e < 8; ++e) if (l[e] > l[i0]) i0 = e;
    int i1 = (i0 == 0) ? 1 : 0;
#pragma unroll
    for (int e = 0; e < 8; ++e) if (e != i0 && l[e] > l[i1]) i1 = e;
    double z = exp(l[i1] - l[i0]);
    float w0 = (float)(1.0 / (1.0 + z));
    float w1 = (float)(z / (1.0 + z));
    ridx[2 * b] = i0; ridx[2 * b + 1] = i1;
    rw[2 * b] = w0;   rw[2 * b + 1] = w1;
  }
}

// ---- per-block histogram over 16 (k,e) buckets; LDS atomics only ----
__global__ void hist_tok(const int* __restrict__ ridx, int* __restrict__ partials) {
  __shared__ int h[16];
  int t = threadIdx.x;
  if (t < 16) h[t] = 0;
  __syncthreads();
  int t0 = blockIdx.x * 512;
  for (int i = t; i < 512; i += 256) {
    int tok = t0 + i;
    atomicAdd(&h[ridx[2 * tok]], 1);
    atomicAdd(&h[8 + ridx[2 * tok + 1]], 1);
  }
  __syncthreads();
  if (t < 16) partials[blockIdx.x * 16 + t] = h[t];
}

__global__ void scan_small(const int* __restrict__ partials, int* __restrict__ base,
                           int* __restrict__ cnts, int* __restrict__ offs) {
  __shared__ int c[16], o[16];
  int j = threadIdx.x;
  if (j < 16) {
    int s = 0;
    for (int b = 0; b < 32; ++b) s += partials[b * 16 + j];
    c[j] = s; cnts[j] = s;
  }
  __syncthreads();
  if (j < 2) {
    int a = 0;
    for (int e = 0; e < 8; ++e) { o[j * 8 + e] = a; a += c[j * 8 + e]; }
  }
  __syncthreads();
  if (j < 16) {
    int r = o[j];
    offs[j] = o[j];
    for (int b = 0; b < 32; ++b) { base[b * 16 + j] = r; r += partials[b * 16 + j]; }
  }
}

__global__ void scatter_tok(const int* __restrict__ ridx, const float* __restrict__ rw,
                            const int* __restrict__ base,
                            int* __restrict__ lists0, float* __restrict__ elw0,
                            int* __restrict__ lists1, float* __restrict__ elw1) {
  __shared__ int h[16];
  int t = threadIdx.x;
  if (t < 16) h[t] = 0;
  __syncthreads();
  int t0 = blockIdx.x * 512;
  const int* bb = base + blockIdx.x * 16;
  for (int i = t; i < 512; i += 256) {
    int tok = t0 + i;
    int e0 = ridx[2 * tok], e1 = ridx[2 * tok + 1];
    int r0 = atomicAdd(&h[e0], 1);
    int r1 = atomicAdd(&h[8 + e1], 1);
    int p0 = bb[e0] + r0;
    int p1 = bb[8 + e1] + r1;
    lists0[p0] = tok; elw0[p0] = rw[2 * tok];
    lists1[p1] = tok; elw1[p1] = rw[2 * tok + 1];
  }
}

// ===== 128x128 single-buffer BK=64 grouped GEMM (R9/R12 structure) =====
// + T5: s_setprio(1) around the MFMA cluster. 4 independent barrier-groups/CU
// at staggered phases -> MFMA-phase waves get scheduler preference over
// waves issuing stage loads (m191 independent-blocks mechanism).
template <int ADD>
__global__ __launch_bounds__(256, 4)
void moe_gemm(const short* __restrict__ xb, const short* __restrict__ wt,
              const float* __restrict__ eb, const int* __restrict__ cnts,
              const int* __restrict__ offs, const int* __restrict__ lists,
              const float* __restrict__ elw, float* __restrict__ out) {
  __shared__ short As[TM * BK];   // 16 KiB, XOR-swizzled storage
  __shared__ short Bs[TN * BK];   // 16 KiB

  int bid = blockIdx.x;
  int xcd = bid & 7;
  int j = bid >> 3;                    // 0..271 within XCD
  int mt = xcd * 17 + (j >> 4);        // 17-mt band per XCD
  int nt = j & 15;                     // nt fastest -> concurrent nt share A

  int e = 0, cnt = 0;
  for (; e < NE; ++e) {
    cnt = cnts[e];
    int te = (cnt + TM - 1) >> 7;
    if (mt < te) break;
    mt -= te;
  }
  if (e >= NE) return;

  int m0 = mt * TM;
  int n0 = nt * TN;
  int off_e = offs[e];
  int tid = threadIdx.x;
  int lane = tid & 63, wid = tid >> 6;
  int wr = wid >> 1, wc = wid & 1;      // 2x2 waves; wave out = 64x64

  // staging coords: linear LDS dest = l*4096B + tid*16B; inverse-swz source col
  int trow = tid >> 3;                  // 0..31
  int scol = ((tid & 7) ^ (trow & 7)) << 3;
  int tok[4];
#pragma unroll
  for (int l = 0; l < 4; ++l) {
    int gr = m0 + l * 32 + trow;
    tok[l] = lists[off_e + ((gr < cnt) ? gr : (cnt - 1))];
  }
  const short* bbase = wt + ((size_t)e * DD + (size_t)(n0 + trow)) * DD + scol;

  // fragment read addressing (swizzle XOR folds to lane&7)
  int lane15 = lane & 15;
  int csw0 = (((lane >> 4)    ) ^ (lane & 7)) << 3;
  int csw1 = (((lane >> 4) + 4) ^ (lane & 7)) << 3;
  int arow = (wr * 64 + lane15) * 64;
  int brow = (wc * 64 + lane15) * 64;

  f32x4 acc[4][4];
#pragma unroll
  for (int i = 0; i < 4; ++i)
#pragma unroll
    for (int j2 = 0; j2 < 4; ++j2) acc[i][j2] = (f32x4){0.f, 0.f, 0.f, 0.f};

#pragma unroll 1
  for (int kt = 0; kt < NKT; ++kt) {
    int ko = kt * BK + scol;
#pragma unroll
    for (int l = 0; l < 4; ++l) {
      gload16(xb + ((size_t)tok[l] << 11) + ko, &As[l * 2048 + tid * 8]);
      gload16(bbase + (size_t)(l * 32) * DD + kt * BK, &Bs[l * 2048 + tid * 8]);
    }
    __syncthreads();
    bf16x8 bfr[4][2];
#pragma unroll
    for (int j2 = 0; j2 < 4; ++j2) {
      int br = brow + j2 * 16 * 64;
      bfr[j2][0] = *(const bf16x8*)&Bs[br + csw0];
      bfr[j2][1] = *(const bf16x8*)&Bs[br + csw1];
    }
    __builtin_amdgcn_s_setprio(1);
#pragma unroll
    for (int i = 0; i < 4; ++i) {
      int ar = arow + i * 16 * 64;
      bf16x8 a0 = *(const bf16x8*)&As[ar + csw0];
      bf16x8 a1 = *(const bf16x8*)&As[ar + csw1];
#pragma unroll
      for (int j2 = 0; j2 < 4; ++j2) {
        acc[i][j2] = __builtin_amdgcn_mfma_f32_16x16x32_bf16(a0, bfr[j2][0], acc[i][j2], 0, 0, 0);
        acc[i][j2] = __builtin_amdgcn_mfma_f32_16x16x32_bf16(a1, bfr[j2][1], acc[i][j2], 0, 0, 0);
      }
    }
    __builtin_amdgcn_s_setprio(0);
    __syncthreads();
  }

  // epilogue: bias + relu + gate-weight; nontemporal store / load-add-store
  int r0 = (lane >> 4) << 2;
#pragma unroll
  for (int i = 0; i < 4; ++i) {
    int mloc = wr * 64 + i * 16 + r0;
#pragma unroll
    for (int r = 0; r < 4; ++r) {
      int gr = m0 + mloc + r;
      if (gr >= cnt) continue;
      int tokr = lists[off_e + gr];
      float wgt = elw[off_e + gr];
      float* orow = out + (size_t)tokr * DD;
#pragma unroll
      for (int j2 = 0; j2 < 4; ++j2) {
        int n = n0 + wc * 64 + j2 * 16 + lane15;
        float v = acc[i][j2][r] + eb[e * DD + n];
        v = fmaxf(v, 0.f) * wgt;
        if (ADD) v += __builtin_nontemporal_load(&orow[n]);
        __builtin_nontemporal_store(v, &orow[n]);
      }
    }
  }
}

extern "C" void kernel_launch(void* const* d_in, const int* in_sizes, int n_in,
                              void* d_out, int out_size, void* d_ws, size_t ws_size,
                              hipStream_t stream) {
  const float* x   = (const float*)d_in[0];
  const float* ewt = (const float*)d_in[1];
  const float* eb  = (const float*)d_in[2];
  const float* gw  = (const float*)d_in[3];
  const float* gb  = (const float*)d_in[4];
  float* out = (float*)d_out;

  char* ws = (char*)d_ws;
  short* xb      = (short*)(ws);                     // 67108864 B
  short* wt      = (short*)(ws + 67108864);          // 67108864 B
  int*   ridx    = (int*)  (ws + 134217728);         // 131072 B
  float* rw      = (float*)(ws + 134348800);         // 131072 B
  int*   lists0  = (int*)  (ws + 134479872);         // 65536 B
  float* elw0    = (float*)(ws + 134545408);         // 65536 B
  int*   lists1  = (int*)  (ws + 134610944);         // 65536 B
  float* elw1    = (float*)(ws + 134676480);         // 65536 B
  int*   partials= (int*)  (ws + 134742016);         // 2048 B
  int*   base    = (int*)  (ws + 134744064);         // 2048 B
  int*   cnts    = (int*)  (ws + 134746112);         // 64 B
  int*   offs    = (int*)  (ws + 134746176);         // 64 B

  conv_wT<<<NE * 32 * 32, 256, 0, stream>>>(ewt, wt);
  gate_conv<<<NB / 4, 256, 0, stream>>>(x, gw, gb, xb, ridx, rw);
  hist_tok<<<32, 256, 0, stream>>>(ridx, partials);
  scan_small<<<1, 64, 0, stream>>>(partials, base, cnts, offs);
  scatter_tok<<<32, 256, 0, stream>>>(ridx, rw, base, lists0, elw0, lists1, elw1);
  moe_gemm<0><<<GEMM_GRID, 256, 0, stream>>>(xb, wt, eb, cnts,     offs,     lists0, elw0, out);
  moe_gemm<1><<<GEMM_GRID, 256, 0, stream>>>(xb, wt, eb, cnts + 8, offs + 8, lists1, elw1, out);
}

// Round 14
// 539.341 us; speedup vs baseline: 1.0188x; 1.0188x over previous
//
#include <hip/hip_runtime.h>
#include <hip/hip_bf16.h>
#include <math.h>

#define NB 16384      // tokens
#define DD 2048       // hidden dim
#define NE 8          // experts
#define TM 128
#define TN 128
#define BK 64
#define NKT (DD / BK)                      // 32 K-tiles
#define MT_PER_PASS (NB / TM + NE)         // 136 = 8 XCDs x 17 M-tile band
#define NT_TILES (DD / TN)                 // 16
#define GEMM_GRID (MT_PER_PASS * NT_TILES) // 2176

typedef float f32x4 __attribute__((ext_vector_type(4)));
typedef short bf16x8 __attribute__((ext_vector_type(8)));

__device__ __forceinline__ short f2bf(float f) {
  union { float f; unsigned u; } v; v.f = f;
  unsigned r = (v.u + 0x7FFFu + ((v.u >> 16) & 1u)) >> 16;  // RNE
  return (short)r;
}

__device__ __forceinline__ void gload16(const void* g, void* l) {
  __builtin_amdgcn_global_load_lds((const __attribute__((address_space(1))) void*)g,
                                   (__attribute__((address_space(3))) void*)l,
                                   16, 0, 0);
}

// ---- expert_w (E,D,D fp32, [d][f]) -> bf16 transposed Wt[e][f][d] ----
__global__ void conv_wT(const float* __restrict__ w, short* __restrict__ wt) {
  __shared__ float tile[64][68];
  int bid = blockIdx.x;
  int e = bid >> 10;
  int tt = bid & 1023;
  int d0 = (tt >> 5) << 6;
  int f0 = (tt & 31) << 6;
  const float* we = w + (size_t)e * DD * DD;
  int t = threadIdx.x;
  int col = (t & 15) << 2;
#pragma unroll
  for (int p = 0; p < 4; ++p) {
    int dl = (t >> 4) + p * 16;
    f32x4 v = *(const f32x4*)(we + (size_t)(d0 + dl) * DD + f0 + col);
    *(f32x4*)&tile[dl][col] = v;
  }
  __syncthreads();
  int fl = t >> 2;
  int ds = (t & 3) << 4;
  short tmp[16];
#pragma unroll
  for (int j = 0; j < 16; ++j) tmp[j] = f2bf(tile[ds + j][fl]);
  short* dst = wt + (size_t)e * DD * DD + (size_t)(f0 + fl) * DD + d0 + ds;
  *(bf16x8*)dst = *(const bf16x8*)tmp;
  *(bf16x8*)(dst + 8) = *(const bf16x8*)(tmp + 8);
}

// ---- fused: x -> bf16 conversion + gate logits (fp64) + top-2 softmax ----
__global__ void gate_conv(const float* __restrict__ x, const float* __restrict__ gw,
                          const float* __restrict__ gb, short* __restrict__ xb,
                          int* __restrict__ ridx, float* __restrict__ rw) {
  int wid = threadIdx.x >> 6;
  int lane = threadIdx.x & 63;
  int b = blockIdx.x * 4 + wid;
  const float* xr = x + (size_t)b * DD;
  short* xbr = xb + (size_t)b * DD;
  double acc[8];
#pragma unroll
  for (int e = 0; e < 8; ++e) acc[e] = 0.0;
#pragma unroll
  for (int it = 0; it < 4; ++it) {
    int d8 = (it * 64 + lane) * 8;
    f32x4 a = *(const f32x4*)(xr + d8);
    f32x4 c = *(const f32x4*)(xr + d8 + 4);
    bf16x8 o;
    o[0] = f2bf(a[0]); o[1] = f2bf(a[1]); o[2] = f2bf(a[2]); o[3] = f2bf(a[3]);
    o[4] = f2bf(c[0]); o[5] = f2bf(c[1]); o[6] = f2bf(c[2]); o[7] = f2bf(c[3]);
    *(bf16x8*)(xbr + d8) = o;
#pragma unroll
    for (int j = 0; j < 8; ++j) {
      float xv = (j < 4) ? a[j] : c[j - 4];
      double xd = (double)xv;
      f32x4 g0 = *(const f32x4*)(gw + (size_t)(d8 + j) * 8);
      f32x4 g1 = *(const f32x4*)(gw + (size_t)(d8 + j) * 8 + 4);
      acc[0] += xd * g0[0]; acc[1] += xd * g0[1];
      acc[2] += xd * g0[2]; acc[3] += xd * g0[3];
      acc[4] += xd * g1[0]; acc[5] += xd * g1[1];
      acc[6] += xd * g1[2]; acc[7] += xd * g1[3];
    }
  }
#pragma unroll
  for (int off = 32; off > 0; off >>= 1) {
#pragma unroll
    for (int e = 0; e < 8; ++e) acc[e] += __shfl_down(acc[e], off);
  }
  if (lane == 0) {
    double l[8];
#pragma unroll
    for (int e = 0; e < 8; ++e) l[e] = acc[e] + (double)gb[e];
    int i0 = 0;
#pragma unroll
    for (int e = 1; e < 8; ++e) if (l[e] > l[i0]) i0 = e;
    int i1 = (i0 == 0) ? 1 : 0;
#pragma unroll
    for (int e = 0; e < 8; ++e) if (e != i0 && l[e] > l[i1]) i1 = e;
    double z = exp(l[i1] - l[i0]);
    float w0 = (float)(1.0 / (1.0 + z));
    float w1 = (float)(z / (1.0 + z));
    ridx[2 * b] = i0; ridx[2 * b + 1] = i1;
    rw[2 * b] = w0;   rw[2 * b + 1] = w1;
  }
}

// ---- per-block histogram over 16 (k,e) buckets; LDS atomics only ----
__global__ void hist_tok(const int* __restrict__ ridx, int* __restrict__ partials) {
  __shared__ int h[16];
  int t = threadIdx.x;
  if (t < 16) h[t] = 0;
  __syncthreads();
  int t0 = blockIdx.x * 512;
  for (int i = t; i < 512; i += 256) {
    int tok = t0 + i;
    atomicAdd(&h[ridx[2 * tok]], 1);
    atomicAdd(&h[8 + ridx[2 * tok + 1]], 1);
  }
  __syncthreads();
  if (t < 16) partials[blockIdx.x * 16 + t] = h[t];
}

__global__ void scan_small(const int* __restrict__ partials, int* __restrict__ base,
                           int* __restrict__ cnts, int* __restrict__ offs) {
  __shared__ int c[16], o[16];
  int j = threadIdx.x;
  if (j < 16) {
    int s = 0;
    for (int b = 0; b < 32; ++b) s += partials[b * 16 + j];
    c[j] = s; cnts[j] = s;
  }
  __syncthreads();
  if (j < 2) {
    int a = 0;
    for (int e = 0; e < 8; ++e) { o[j * 8 + e] = a; a += c[j * 8 + e]; }
  }
  __syncthreads();
  if (j < 16) {
    int r = o[j];
    offs[j] = o[j];
    for (int b = 0; b < 32; ++b) { base[b * 16 + j] = r; r += partials[b * 16 + j]; }
  }
}

__global__ void scatter_tok(const int* __restrict__ ridx, const float* __restrict__ rw,
                            const int* __restrict__ base,
                            int* __restrict__ lists0, float* __restrict__ elw0,
                            int* __restrict__ lists1, float* __restrict__ elw1) {
  __shared__ int h[16];
  int t = threadIdx.x;
  if (t < 16) h[t] = 0;
  __syncthreads();
  int t0 = blockIdx.x * 512;
  const int* bb = base + blockIdx.x * 16;
  for (int i = t; i < 512; i += 256) {
    int tok = t0 + i;
    int e0 = ridx[2 * tok], e1 = ridx[2 * tok + 1];
    int r0 = atomicAdd(&h[e0], 1);
    int r1 = atomicAdd(&h[8 + e1], 1);
    int p0 = bb[e0] + r0;
    int p1 = bb[8 + e1] + r1;
    lists0[p0] = tok; elw0[p0] = rw[2 * tok];
    lists1[p1] = tok; elw1[p1] = rw[2 * tok + 1];
  }
}

// ===== 128x128 single-buffer BK=64 grouped GEMM (R9/R12 structure, BEST) =====
// L2-locality mapping: XCD x owns a 17-mt band x all 16 nt, nt-FASTEST, so the
// ~128 resident blocks/XCD cover ~8 mt x 16 nt -> A-window ~4 MB fits that
// XCD's L2; each A-tile is one L3 fetch + 15 L2 hits.
// Register budget: acc 64 AGPR + 60 VGPR = 124 unified -> 16 waves/CU bucket
// -> 4 independent barrier-groups/CU (the measured optimum; every perturbation
// of tile/BK/buffering/priority measured worse, R3-R8, R13).
template <int ADD>
__global__ __launch_bounds__(256, 4)
void moe_gemm(const short* __restrict__ xb, const short* __restrict__ wt,
              const float* __restrict__ eb, const int* __restrict__ cnts,
              const int* __restrict__ offs, const int* __restrict__ lists,
              const float* __restrict__ elw, float* __restrict__ out) {
  __shared__ short As[TM * BK];   // 16 KiB, XOR-swizzled storage
  __shared__ short Bs[TN * BK];   // 16 KiB

  int bid = blockIdx.x;
  int xcd = bid & 7;
  int j = bid >> 3;                    // 0..271 within XCD
  int mt = xcd * 17 + (j >> 4);        // 17-mt band per XCD
  int nt = j & 15;                     // nt fastest -> concurrent nt share A

  int e = 0, cnt = 0;
  for (; e < NE; ++e) {
    cnt = cnts[e];
    int te = (cnt + TM - 1) >> 7;
    if (mt < te) break;
    mt -= te;
  }
  if (e >= NE) return;

  int m0 = mt * TM;
  int n0 = nt * TN;
  int off_e = offs[e];
  int tid = threadIdx.x;
  int lane = tid & 63, wid = tid >> 6;
  int wr = wid >> 1, wc = wid & 1;      // 2x2 waves; wave out = 64x64

  // staging coords: linear LDS dest = l*4096B + tid*16B; inverse-swz source col
  int trow = tid >> 3;                  // 0..31
  int scol = ((tid & 7) ^ (trow & 7)) << 3;
  int tok[4];
#pragma unroll
  for (int l = 0; l < 4; ++l) {
    int gr = m0 + l * 32 + trow;
    tok[l] = lists[off_e + ((gr < cnt) ? gr : (cnt - 1))];
  }
  const short* bbase = wt + ((size_t)e * DD + (size_t)(n0 + trow)) * DD + scol;

  // fragment read addressing (swizzle XOR folds to lane&7)
  int lane15 = lane & 15;
  int csw0 = (((lane >> 4)    ) ^ (lane & 7)) << 3;
  int csw1 = (((lane >> 4) + 4) ^ (lane & 7)) << 3;
  int arow = (wr * 64 + lane15) * 64;
  int brow = (wc * 64 + lane15) * 64;

  f32x4 acc[4][4];
#pragma unroll
  for (int i = 0; i < 4; ++i)
#pragma unroll
    for (int j2 = 0; j2 < 4; ++j2) acc[i][j2] = (f32x4){0.f, 0.f, 0.f, 0.f};

#pragma unroll 1
  for (int kt = 0; kt < NKT; ++kt) {
    int ko = kt * BK + scol;
#pragma unroll
    for (int l = 0; l < 4; ++l) {
      gload16(xb + ((size_t)tok[l] << 11) + ko, &As[l * 2048 + tid * 8]);
      gload16(bbase + (size_t)(l * 32) * DD + kt * BK, &Bs[l * 2048 + tid * 8]);
    }
    __syncthreads();
    bf16x8 bfr[4][2];
#pragma unroll
    for (int j2 = 0; j2 < 4; ++j2) {
      int br = brow + j2 * 16 * 64;
      bfr[j2][0] = *(const bf16x8*)&Bs[br + csw0];
      bfr[j2][1] = *(const bf16x8*)&Bs[br + csw1];
    }
#pragma unroll
    for (int i = 0; i < 4; ++i) {
      int ar = arow + i * 16 * 64;
      bf16x8 a0 = *(const bf16x8*)&As[ar + csw0];
      bf16x8 a1 = *(const bf16x8*)&As[ar + csw1];
#pragma unroll
      for (int j2 = 0; j2 < 4; ++j2) {
        acc[i][j2] = __builtin_amdgcn_mfma_f32_16x16x32_bf16(a0, bfr[j2][0], acc[i][j2], 0, 0, 0);
        acc[i][j2] = __builtin_amdgcn_mfma_f32_16x16x32_bf16(a1, bfr[j2][1], acc[i][j2], 0, 0, 0);
      }
    }
    __syncthreads();
  }

  // epilogue: bias + relu + gate-weight; nontemporal store / load-add-store
  int r0 = (lane >> 4) << 2;
#pragma unroll
  for (int i = 0; i < 4; ++i) {
    int mloc = wr * 64 + i * 16 + r0;
#pragma unroll
    for (int r = 0; r < 4; ++r) {
      int gr = m0 + mloc + r;
      if (gr >= cnt) continue;
      int tokr = lists[off_e + gr];
      float wgt = elw[off_e + gr];
      float* orow = out + (size_t)tokr * DD;
#pragma unroll
      for (int j2 = 0; j2 < 4; ++j2) {
        int n = n0 + wc * 64 + j2 * 16 + lane15;
        float v = acc[i][j2][r] + eb[e * DD + n];
        v = fmaxf(v, 0.f) * wgt;
        if (ADD) v += __builtin_nontemporal_load(&orow[n]);
        __builtin_nontemporal_store(v, &orow[n]);
      }
    }
  }
}

extern "C" void kernel_launch(void* const* d_in, const int* in_sizes, int n_in,
                              void* d_out, int out_size, void* d_ws, size_t ws_size,
                              hipStream_t stream) {
  const float* x   = (const float*)d_in[0];
  const float* ewt = (const float*)d_in[1];
  const float* eb  = (const float*)d_in[2];
  const float* gw  = (const float*)d_in[3];
  const float* gb  = (const float*)d_in[4];
  float* out = (float*)d_out;

  char* ws = (char*)d_ws;
  short* xb      = (short*)(ws);                     // 67108864 B
  short* wt      = (short*)(ws + 67108864);          // 67108864 B
  int*   ridx    = (int*)  (ws + 134217728);         // 131072 B
  float* rw      = (float*)(ws + 134348800);         // 131072 B
  int*   lists0  = (int*)  (ws + 134479872);         // 65536 B
  float* elw0    = (float*)(ws + 134545408);         // 65536 B
  int*   lists1  = (int*)  (ws + 134610944);         // 65536 B
  float* elw1    = (float*)(ws + 134676480);         // 65536 B
  int*   partials= (int*)  (ws + 134742016);         // 2048 B
  int*   base    = (int*)  (ws + 134744064);         // 2048 B
  int*   cnts    = (int*)  (ws + 134746112);         // 64 B
  int*   offs    = (int*)  (ws + 134746176);         // 64 B

  conv_wT<<<NE * 32 * 32, 256, 0, stream>>>(ewt, wt);
  gate_conv<<<NB / 4, 256, 0, stream>>>(x, gw, gb, xb, ridx, rw);
  hist_tok<<<32, 256, 0, stream>>>(ridx, partials);
  scan_small<<<1, 64, 0, stream>>>(partials, base, cnts, offs);
  scatter_tok<<<32, 256, 0, stream>>>(ridx, rw, base, lists0, elw0, lists1, elw1);
  moe_gemm<0><<<GEMM_GRID, 256, 0, stream>>>(xb, wt, eb, cnts,     offs,     lists0, elw0, out);
  moe_gemm<1><<<GEMM_GRID, 256, 0, stream>>>(xb, wt, eb, cnts + 8, offs + 8, lists1, elw1, out);
}